// Round 1
// baseline (31115.881 us; speedup 1.0000x reference)
//
#include <hip/hip_runtime.h>
#include <hip/hip_bf16.h>

#define SEQ   512
#define BATCH 256
#define DIN   512
#define DLAT  1024

typedef __attribute__((ext_vector_type(8))) short bf16x8;
typedef __attribute__((ext_vector_type(4))) float f32x4;

__device__ __forceinline__ unsigned short f2bf(float f) {
    union { float f; unsigned u; } v; v.f = f;
    unsigned r = v.u + 0x7FFFu + ((v.u >> 16) & 1u);   // RNE
    return (unsigned short)(r >> 16);
}

__global__ void convert_weights(const float* __restrict__ Wi, const float* __restrict__ Wh,
                                unsigned short* __restrict__ Wib, unsigned short* __restrict__ Whb) {
    const int nWi = DLAT * DIN;
    const int nWh = DLAT * DLAT;
    for (int idx = blockIdx.x * blockDim.x + threadIdx.x; idx < nWi + nWh;
         idx += gridDim.x * blockDim.x) {
        if (idx < nWi) Wib[idx] = f2bf(Wi[idx]);
        else           Whb[idx - nWi] = f2bf(Wh[idx - nWi]);
    }
}

// Phase 1: xi = x @ Wi^T. M=SEQ*BATCH, K=DIN, N=DLAT.
// 1024 thr = 16 waves. Block tile 64(M) x 256(N). grid = (M/64)*(DLAT/256).
// Wave w: m-strip (w&3)*16 within the 64, n-range (w>>2)*64 (4 n-tiles).
__global__ __launch_bounds__(1024) void xproj_kernel(const float* __restrict__ x,
                                                     const unsigned short* __restrict__ Wib,
                                                     float* __restrict__ xi) {
    const int tid  = threadIdx.x;
    const int lane = tid & 63;
    const int w    = tid >> 6;
    const int l15  = lane & 15;
    const int l4   = lane >> 4;               // 0..3 (K-group for A/B frags)
    const int mblk = blockIdx.x >> 2;
    const int nblk = blockIdx.x & 3;
    const size_t m0 = (size_t)mblk * 64 + (w & 3) * 16;
    const int    n0 = nblk * 256 + (w >> 2) * 64;

    const float* xp = x + (m0 + l15) * DIN + l4 * 8;

    f32x4 acc[4];
    #pragma unroll
    for (int j = 0; j < 4; ++j) acc[j] = (f32x4)0.f;

    const unsigned short* bp[4];
    #pragma unroll
    for (int j = 0; j < 4; ++j)
        bp[j] = Wib + (size_t)(n0 + j * 16 + l15) * DIN + l4 * 8;

    #pragma unroll 4
    for (int kc = 0; kc < DIN / 32; ++kc) {
        f32x4 a0 = *(const f32x4*)(xp + kc * 32);
        f32x4 a1 = *(const f32x4*)(xp + kc * 32 + 4);
        bf16x8 af;
        #pragma unroll
        for (int i = 0; i < 4; ++i) { af[i] = (short)f2bf(a0[i]); af[i + 4] = (short)f2bf(a1[i]); }
        #pragma unroll
        for (int j = 0; j < 4; ++j) {
            bf16x8 bf = *(const bf16x8*)(bp[j] + kc * 32);
            acc[j] = __builtin_amdgcn_mfma_f32_16x16x32_bf16(af, bf, acc[j], 0, 0, 0);
        }
    }
    #pragma unroll
    for (int j = 0; j < 4; ++j) {
        const int col = n0 + j * 16 + l15;
        #pragma unroll
        for (int i = 0; i < 4; ++i)
            xi[(m0 + l4 * 4 + i) * DLAT + col] = acc[j][i];
    }
}

// Phase 2: sequential scan. 16 blocks, one per 16-batch group; 1024 thr = 16 waves.
// Wave w owns output columns [64w, 64w+64) (4 MFMA n-tiles).
// h (16 x 1024 bf16) lives in LDS (A operand). W_h bf16 streams from L2 (B operand).
// hs region of d_out holds xi on entry; overwritten in place with h each step.
__global__ __launch_bounds__(1024) void rnn_scan(const unsigned short* __restrict__ Whb,
                                                 const float* __restrict__ bh,
                                                 float* __restrict__ hs,
                                                 float* __restrict__ hfin) {
    __shared__ unsigned short hlds[16][DLAT + 8];   // +8 bf16 pad -> 2-way max bank alias

    const int tid  = threadIdx.x;
    const int lane = tid & 63;
    const int w    = tid >> 6;        // 0..15
    const int l15  = lane & 15;
    const int l4   = lane >> 4;       // 0..3
    const int b0   = blockIdx.x * 16; // batch rows [b0, b0+16)

    for (int idx = tid; idx < 16 * (DLAT + 8); idx += 1024)
        ((unsigned short*)hlds)[idx] = 0;

    float bias[4];
    const unsigned short* bbase[4];
    int  cols[4];
    #pragma unroll
    for (int j = 0; j < 4; ++j) {
        cols[j]  = w * 64 + j * 16 + l15;
        bias[j]  = bh[cols[j]];
        bbase[j] = Whb + (size_t)cols[j] * DLAT + l4 * 8;
    }

    __syncthreads();

    for (int t = 0; t < SEQ; ++t) {
        const size_t tb = ((size_t)t * BATCH + b0 + l4 * 4) * DLAT;

        // issue xi loads early; consumed after the K loop (latency hidden by MFMAs)
        float xiv[4][4];
        #pragma unroll
        for (int j = 0; j < 4; ++j)
            #pragma unroll
            for (int i = 0; i < 4; ++i)
                xiv[j][i] = hs[tb + (size_t)i * DLAT + cols[j]];

        f32x4 acc[4];
        #pragma unroll
        for (int j = 0; j < 4; ++j) acc[j] = (f32x4)0.f;

        #pragma unroll 8
        for (int kk = 0; kk < DLAT / 32; ++kk) {
            bf16x8 af = *(const bf16x8*)&hlds[l15][kk * 32 + l4 * 8];
            #pragma unroll
            for (int j = 0; j < 4; ++j) {
                bf16x8 bf = *(const bf16x8*)(bbase[j] + kk * 32);
                acc[j] = __builtin_amdgcn_mfma_f32_16x16x32_bf16(af, bf, acc[j], 0, 0, 0);
            }
        }

        __syncthreads();   // everyone done reading hlds for step t

        #pragma unroll
        for (int j = 0; j < 4; ++j) {
            #pragma unroll
            for (int i = 0; i < 4; ++i) {
                float v = acc[j][i] + xiv[j][i] + bias[j];
                v = fminf(fmaxf(v, -15.f), 15.f);
                float e = __expf(2.f * v);
                float h = 1.f - 2.f * __builtin_amdgcn_rcpf(e + 1.f);  // tanh(v)
                hs[tb + (size_t)i * DLAT + cols[j]] = h;               // overwrite xi with h
                hlds[l4 * 4 + i][cols[j]] = f2bf(h);
                if (t == SEQ - 1)
                    hfin[(size_t)(b0 + l4 * 4 + i) * DLAT + cols[j]] = h;
            }
        }

        __syncthreads();   // hlds ready for step t+1
    }
}

extern "C" void kernel_launch(void* const* d_in, const int* in_sizes, int n_in,
                              void* d_out, int out_size, void* d_ws, size_t ws_size,
                              hipStream_t stream) {
    const float* x  = (const float*)d_in[0];
    const float* Wi = (const float*)d_in[1];
    const float* Wh = (const float*)d_in[2];
    const float* bh = (const float*)d_in[3];

    float* out  = (float*)d_out;
    float* hfin = out;                                  // [BATCH, DLAT]
    float* hs   = out + (size_t)BATCH * DLAT;           // [SEQ, BATCH, DLAT], doubles as xi

    unsigned short* Wib = (unsigned short*)d_ws;                      // 1 MB
    unsigned short* Whb = Wib + (size_t)DLAT * DIN;                   // 2 MB

    convert_weights<<<512, 256, 0, stream>>>(Wi, Wh, Wib, Whb);

    const int M = SEQ * BATCH;
    xproj_kernel<<<(M / 64) * (DLAT / 256), 1024, 0, stream>>>(x, Wib, hs);

    rnn_scan<<<BATCH / 16, 1024, 0, stream>>>(Whb, bh, hs, hfin);
}

// Round 2
// 10999.541 us; speedup vs baseline: 2.8288x; 2.8288x over previous
//
#include <hip/hip_runtime.h>
#include <hip/hip_bf16.h>
#include <hip/hip_cooperative_groups.h>

namespace cg = cooperative_groups;

#define SEQ   512
#define BATCH 256
#define DIN   512
#define DLAT  1024

#define NBG   16          // batch groups of 16 rows
#define NCG   8           // column groups of 128 cols
#define SCAN_THREADS 512  // 8 waves, 16 cols each

typedef __attribute__((ext_vector_type(8))) short bf16x8;
typedef __attribute__((ext_vector_type(4))) float f32x4;

__device__ __forceinline__ unsigned short f2bf(float f) {
    union { float f; unsigned u; } v; v.f = f;
    unsigned r = v.u + 0x7FFFu + ((v.u >> 16) & 1u);   // RNE
    return (unsigned short)(r >> 16);
}

__global__ void convert_weights(const float* __restrict__ Wi, const float* __restrict__ Wh,
                                unsigned short* __restrict__ Wib, unsigned short* __restrict__ Whb) {
    const int nWi = DLAT * DIN;
    const int nWh = DLAT * DLAT;
    for (int idx = blockIdx.x * blockDim.x + threadIdx.x; idx < nWi + nWh;
         idx += gridDim.x * blockDim.x) {
        if (idx < nWi) Wib[idx] = f2bf(Wi[idx]);
        else           Whb[idx - nWi] = f2bf(Wh[idx - nWi]);
    }
}

// Phase 1: xi = x @ Wi^T. M=SEQ*BATCH, K=DIN, N=DLAT. (validated round 1)
__global__ __launch_bounds__(1024) void xproj_kernel(const float* __restrict__ x,
                                                     const unsigned short* __restrict__ Wib,
                                                     float* __restrict__ xi) {
    const int tid  = threadIdx.x;
    const int lane = tid & 63;
    const int w    = tid >> 6;
    const int l15  = lane & 15;
    const int l4   = lane >> 4;
    const int mblk = blockIdx.x >> 2;
    const int nblk = blockIdx.x & 3;
    const size_t m0 = (size_t)mblk * 64 + (w & 3) * 16;
    const int    n0 = nblk * 256 + (w >> 2) * 64;

    const float* xp = x + (m0 + l15) * DIN + l4 * 8;

    f32x4 acc[4];
    #pragma unroll
    for (int j = 0; j < 4; ++j) acc[j] = (f32x4)0.f;

    const unsigned short* bp[4];
    #pragma unroll
    for (int j = 0; j < 4; ++j)
        bp[j] = Wib + (size_t)(n0 + j * 16 + l15) * DIN + l4 * 8;

    #pragma unroll 4
    for (int kc = 0; kc < DIN / 32; ++kc) {
        f32x4 a0 = *(const f32x4*)(xp + kc * 32);
        f32x4 a1 = *(const f32x4*)(xp + kc * 32 + 4);
        bf16x8 af;
        #pragma unroll
        for (int i = 0; i < 4; ++i) { af[i] = (short)f2bf(a0[i]); af[i + 4] = (short)f2bf(a1[i]); }
        #pragma unroll
        for (int j = 0; j < 4; ++j) {
            bf16x8 bf = *(const bf16x8*)(bp[j] + kc * 32);
            acc[j] = __builtin_amdgcn_mfma_f32_16x16x32_bf16(af, bf, acc[j], 0, 0, 0);
        }
    }
    #pragma unroll
    for (int j = 0; j < 4; ++j) {
        const int col = n0 + j * 16 + l15;
        #pragma unroll
        for (int i = 0; i < 4; ++i)
            xi[(m0 + l4 * 4 + i) * DLAT + col] = acc[j][i];
    }
}

// Phase 2: cooperative scan. 128 blocks = 16 bg x 8 cg, 512 thr (8 waves).
// Wave w owns 16 output cols; its W_h slice (16x1024 bf16 = 128 VGPR) lives in
// REGISTERS for the whole scan. h exchanged via double-buffered global hbuf
// (bf16), staged to LDS each step. One grid.sync() per step.
__global__ __launch_bounds__(SCAN_THREADS, 1) void rnn_scan(
        const unsigned short* __restrict__ Whb,
        const float* __restrict__ bh,
        float* __restrict__ hs,          // xi on entry, overwritten with h
        float* __restrict__ hfin,
        unsigned short* __restrict__ hbuf) {   // [2][BATCH][DLAT] bf16
    __shared__ unsigned short hlds[16][DLAT + 8];   // +8 pad -> 2-way alias (free)

    const int tid  = threadIdx.x;
    const int lane = tid & 63;
    const int w    = tid >> 6;        // 0..7
    const int l15  = lane & 15;
    const int l4   = lane >> 4;       // 0..3
    const int bg   = blockIdx.x >> 3; // 0..15
    const int cg   = blockIdx.x & 7;  // 0..7
    const int b0   = bg * 16;
    const int col  = cg * 128 + w * 16 + l15;   // this lane's output column

    // ---- W_h fragments resident in VGPRs (32 x bf16x8 = 128 VGPRs) ----
    bf16x8 wf[32];
    {
        const unsigned short* wp = Whb + (size_t)col * DLAT + l4 * 8;
        #pragma unroll
        for (int kk = 0; kk < 32; ++kk)
            wf[kk] = *(const bf16x8*)(wp + kk * 32);
    }
    const float bias = bh[col];

    cg::grid_group grid = cg::this_grid();

    for (int t = 0; t < SEQ; ++t) {
        const size_t tb = ((size_t)t * BATCH + b0) * DLAT;

        // prefetch xi for this step (4 scalars; latency hides under stage+K-loop)
        float xiv[4];
        #pragma unroll
        for (int i = 0; i < 4; ++i)
            xiv[i] = hs[tb + (size_t)(l4 * 4 + i) * DLAT + col];

        if (t > 0) {
            // stage h_prev (16x1024 bf16 = 32 KB) from hbuf[(t+1)&1] into LDS
            const unsigned short* src = hbuf + ((size_t)((t + 1) & 1) * BATCH + b0) * DLAT;
            #pragma unroll
            for (int q = 0; q < 4; ++q) {
                const int o = (q * SCAN_THREADS + tid) * 8;   // element offset
                bf16x8 v = *(const bf16x8*)(src + o);
                *(bf16x8*)&hlds[o >> 10][o & 1023] = v;
            }
        }
        __syncthreads();

        f32x4 acc0 = (f32x4)0.f, acc1 = (f32x4)0.f;
        if (t > 0) {
            #pragma unroll
            for (int kk = 0; kk < 32; kk += 2) {
                bf16x8 a0 = *(const bf16x8*)&hlds[l15][kk * 32 + l4 * 8];
                bf16x8 a1 = *(const bf16x8*)&hlds[l15][kk * 32 + 32 + l4 * 8];
                acc0 = __builtin_amdgcn_mfma_f32_16x16x32_bf16(a0, wf[kk],     acc0, 0, 0, 0);
                acc1 = __builtin_amdgcn_mfma_f32_16x16x32_bf16(a1, wf[kk + 1], acc1, 0, 0, 0);
            }
        }

        unsigned short* dst = hbuf + ((size_t)(t & 1) * BATCH + b0) * DLAT;
        #pragma unroll
        for (int i = 0; i < 4; ++i) {
            float v = acc0[i] + acc1[i] + xiv[i] + bias;
            v = fminf(fmaxf(v, -15.f), 15.f);
            float e = __expf(2.f * v);
            float h = 1.f - 2.f * __builtin_amdgcn_rcpf(e + 1.f);  // tanh(v)
            const int row = l4 * 4 + i;
            hs[tb + (size_t)row * DLAT + col] = h;                 // overwrite xi with h
            dst[(size_t)row * DLAT + col] = f2bf(h);
            if (t == SEQ - 1)
                hfin[(size_t)(b0 + row) * DLAT + col] = h;
        }

        grid.sync();   // h[t] visible device-wide; hbuf[(t+1)&1] free to overwrite
    }
}

extern "C" void kernel_launch(void* const* d_in, const int* in_sizes, int n_in,
                              void* d_out, int out_size, void* d_ws, size_t ws_size,
                              hipStream_t stream) {
    const float* x  = (const float*)d_in[0];
    const float* Wi = (const float*)d_in[1];
    const float* Wh = (const float*)d_in[2];
    const float* bh = (const float*)d_in[3];

    float* out  = (float*)d_out;
    float* hfin = out;                                  // [BATCH, DLAT]
    float* hs   = out + (size_t)BATCH * DLAT;           // [SEQ, BATCH, DLAT], xi then h

    unsigned short* Wib  = (unsigned short*)d_ws;                 // 1 MB
    unsigned short* Whb  = Wib + (size_t)DLAT * DIN;              // 2 MB
    unsigned short* hbuf = Whb + (size_t)DLAT * DLAT;             // 1 MB (2 x 256 x 1024 bf16)

    convert_weights<<<512, 256, 0, stream>>>(Wi, Wh, Wib, Whb);

    const int M = SEQ * BATCH;
    xproj_kernel<<<(M / 64) * (DLAT / 256), 1024, 0, stream>>>(x, Wib, hs);

    void* args[] = { (void*)&Whb, (void*)&bh, (void*)&hs, (void*)&hfin, (void*)&hbuf };
    hipLaunchCooperativeKernel((void*)rnn_scan, dim3(NBG * NCG), dim3(SCAN_THREADS),
                               args, 0, stream);
}